// Round 9
// baseline (247.319 us; speedup 1.0000x reference)
//
#include <hip/hip_runtime.h>
#include <hip/hip_bf16.h>

#define B_ROWS 8192
#define D_DIM  2048
#define C_DIM  1000
#define C_PAD  1024

#define EPS32   1.1920928955078125e-07f
// GAMMA = 1/exp(100) ~ 3.7e-44. GAMMA*rex ~ 1e-40 << ulp(h3~6.9) ~ 4.8e-7,
// so loss == mean(h3) exactly in fp32. rex pipeline deleted (round 5).
// Round 12: rownorm 4 rows/wave ILP-16, finalize 1024-thr — total 232.5us (best).
// Round 13: gemm 128x64 (4/CU); fuse_z 16B stores — 4th fuse_z variant at ~55us,
// declared plateau, frozen.
// Round 14: gemm is L2-DMA-bound (FETCH 33MB = read-once; 786MB L2 DMA, floor
// ~23us, measured ~46): add double-buffer + STAGE(t+1)-before-COMPUTE(t) so the
// DMA queue stays non-empty during compute (DMA:compute ~5:1 per step here,
// unlike m99/m100's compute-rich null regime). LDS 48KB -> still 3 blocks/CU.

typedef __attribute__((ext_vector_type(8))) short short8;   // 8 bf16 = 4 VGPRs
typedef __attribute__((ext_vector_type(4))) float f32x4;    // MFMA accumulator

#define GLOAD_LDS16(gptr, lptr) \
  __builtin_amdgcn_global_load_lds((const __attribute__((address_space(1))) void*)(gptr), \
                                   (__attribute__((address_space(3))) void*)(lptr), 16, 0, 0)

__device__ inline unsigned short f2bf(float x) {
  union { __hip_bfloat16 b; unsigned short u; } cv;
  cv.b = __float2bfloat16(x);
  return cv.u;
}

__device__ inline float wave_red(float v) {
#pragma unroll
  for (int off = 32; off > 0; off >>= 1) v += __shfl_down(v, off, 64);
  return v;
}

// ---- B+P merged (frozen at plateau ~55us):
//   blocks [0,8192):      z_bf = bf16(feature+eps); thread owns 2 CONTIGUOUS
//                         float4-pairs -> 4x16B loads, 1x16B store.
//   blocks [8192,9216):   cast cls_w [1000,2048] -> bf16 padded [1024,2048].
#define ZBLK 8192
__global__ __launch_bounds__(256) void fuse_z(const float4* __restrict__ f4,
                                              const float4* __restrict__ e4,
                                              uint4* __restrict__ z4,
                                              const float* __restrict__ cls_w,
                                              __hip_bfloat16* __restrict__ clsw_bf) {
  int bid = blockIdx.x;
  if (bid < ZBLK) {
    int t = bid * 256 + threadIdx.x;
    int i0 = t * 2;
    float4 f0 = f4[i0], f1 = f4[i0 + 1];
    float4 e0 = e4[i0], e1 = e4[i0 + 1];
    union { unsigned short u[8]; uint4 v; } pz;
    pz.u[0] = f2bf(f0.x + e0.x);
    pz.u[1] = f2bf(f0.y + e0.y);
    pz.u[2] = f2bf(f0.z + e0.z);
    pz.u[3] = f2bf(f0.w + e0.w);
    pz.u[4] = f2bf(f1.x + e1.x);
    pz.u[5] = f2bf(f1.y + e1.y);
    pz.u[6] = f2bf(f1.z + e1.z);
    pz.u[7] = f2bf(f1.w + e1.w);
    z4[t] = pz.v;
  } else {
    int j = ((bid - ZBLK) * 256 + threadIdx.x) * 8;   // elem idx in [1024][2048]
    int row = j >> 11;
    int col = j & 2047;
    union { unsigned short u[8]; uint4 v; } pk;
    if (row < C_DIM) {
      const float* src = cls_w + (size_t)row * D_DIM + col;
#pragma unroll
      for (int i2 = 0; i2 < 8; ++i2) pk.u[i2] = f2bf(src[i2]);
    } else {
#pragma unroll
      for (int i2 = 0; i2 < 8; ++i2) pk.u[i2] = 0;
    }
    *(uint4*)((unsigned short*)clsw_bf + j) = pk.v;
  }
}

// ---- C: probs_raw = z @ cls_w^T + cls_b
// Round 14: BM=128, BN=64, BK=64, double-buffered LDS (48KB, 3 blocks/CU),
// STAGE(t+1) issued before COMPUTE(t). 4 waves as 2x2, each 64x32 (acc[4][2]).
// XOR-swizzle: 16B chunk (row, cc) at slot row*8 + (cc ^ (row&7)).
__global__ __launch_bounds__(256, 3) void gemm_bt(const __hip_bfloat16* __restrict__ A,
                                                  const __hip_bfloat16* __restrict__ Bt,
                                                  const float* __restrict__ cls_b,
                                                  float* __restrict__ out) {
  __shared__ __align__(16) __hip_bfloat16 sA[2][128 * 64];   // 2 x 16 KB
  __shared__ __align__(16) __hip_bfloat16 sB[2][64 * 64];    // 2 x  8 KB
  const int tid = threadIdx.x;
  const int m0 = blockIdx.x * 128;
  const int n0 = blockIdx.y * 64;
  const int w = tid >> 6, lane = tid & 63;
  const int wm = (w & 1) * 64, wn = (w >> 1) * 32;
  const int l15 = lane & 15, quad = lane >> 4;

  // per-thread staging geometry (constant across K)
  const __hip_bfloat16* As[4]; int ja[4];
  const __hip_bfloat16* Bs[2]; int jb[2];
#pragma unroll
  for (int i = 0; i < 4; ++i) {
    int j = i * 256 + tid;            // A: 1024 chunks of 16B (128 rows x 8)
    int row = j >> 3;
    int cc = (j & 7) ^ (row & 7);     // pre-swizzled source (XOR involution)
    As[i] = A + (size_t)(m0 + row) * D_DIM + cc * 8;
    ja[i] = j * 8;
  }
#pragma unroll
  for (int i = 0; i < 2; ++i) {
    int j = i * 256 + tid;            // B: 512 chunks (64 rows x 8)
    int row = j >> 3;
    int cc = (j & 7) ^ (row & 7);
    Bs[i] = Bt + (size_t)(n0 + row) * D_DIM + cc * 8;
    jb[i] = j * 8;
  }

  f32x4 acc[4][2] = {};

  auto STAGE = [&](int buf, int k0) {
#pragma unroll
    for (int i = 0; i < 4; ++i) GLOAD_LDS16(As[i] + k0, &sA[buf][ja[i]]);
#pragma unroll
    for (int i = 0; i < 2; ++i) GLOAD_LDS16(Bs[i] + k0, &sB[buf][jb[i]]);
  };
  auto COMPUTE = [&](const __hip_bfloat16* cA, const __hip_bfloat16* cB) {
#pragma unroll
    for (int kk = 0; kk < 64; kk += 32) {
      const int ccr = (kk >> 3) + quad;   // which 8-elem chunk along K
      short8 af[4], bfr[2];
#pragma unroll
      for (int i = 0; i < 4; ++i) {
        int r = wm + i * 16 + l15;
        af[i] = *(const short8*)&cA[(r * 8 + (ccr ^ (r & 7))) * 8];
      }
#pragma unroll
      for (int jn = 0; jn < 2; ++jn) {
        int r = wn + jn * 16 + l15;
        bfr[jn] = *(const short8*)&cB[(r * 8 + (ccr ^ (r & 7))) * 8];
      }
#pragma unroll
      for (int i = 0; i < 4; ++i)
#pragma unroll
        for (int jn = 0; jn < 2; ++jn)
          acc[i][jn] = __builtin_amdgcn_mfma_f32_16x16x32_bf16(af[i], bfr[jn], acc[i][jn], 0, 0, 0);
    }
  };

  STAGE(0, 0);
  __syncthreads();                      // drains prologue DMA (vmcnt(0))
  int cur = 0;
  for (int k0 = 0; k0 < D_DIM; k0 += 64) {
    if (k0 + 64 < D_DIM) STAGE(cur ^ 1, k0 + 64);   // DMA runs during COMPUTE
    COMPUTE(sA[cur], sB[cur]);
    __syncthreads();                    // drains STAGE(t+1); buf swap is safe
    cur ^= 1;
  }

  // epilogue: C/D layout col=lane&15, row=quad*4+reg  (m89-verified)
#pragma unroll
  for (int i = 0; i < 4; ++i) {
    int row = m0 + wm + i * 16 + quad * 4;
#pragma unroll
    for (int jn = 0; jn < 2; ++jn) {
      int col = n0 + wn + jn * 16 + l15;
      if (col < C_DIM) {
        float bias = cls_b[col];
#pragma unroll
        for (int r = 0; r < 4; ++r)
          out[(size_t)(row + r) * C_DIM + col] = acc[i][jn][r] + bias;
      }
    }
  }
}

// ---- D: per-row normalize+clamp+log, 4 rows per wave (round 12, proven).
__global__ __launch_bounds__(256) void rownorm(float* __restrict__ out,
                                               const int* __restrict__ target,
                                               float* __restrict__ rowloss) {
  const int wv = threadIdx.x >> 6, lane = threadIdx.x & 63;
  const int r0 = blockIdx.x * 16 + wv * 4;

  float v[4][16];
#pragma unroll
  for (int rr = 0; rr < 4; ++rr) {
    const float* row = out + (size_t)(r0 + rr) * C_DIM;
#pragma unroll
    for (int k = 0; k < 4; ++k) {
      int c = k * 256 + lane * 4;
      if (c + 3 < C_DIM) {
        float4 f = *(const float4*)(row + c);
        v[rr][k * 4 + 0] = f.x; v[rr][k * 4 + 1] = f.y;
        v[rr][k * 4 + 2] = f.z; v[rr][k * 4 + 3] = f.w;
      } else {
#pragma unroll
        for (int i = 0; i < 4; ++i) v[rr][k * 4 + i] = (c + i < C_DIM) ? row[c + i] : 0.f;
      }
    }
  }

  float s[4];
#pragma unroll
  for (int rr = 0; rr < 4; ++rr) {
    float a = 0.f;
#pragma unroll
    for (int k = 0; k < 16; ++k) a += v[rr][k];
    s[rr] = a;
  }
#pragma unroll
  for (int rr = 0; rr < 4; ++rr) {
#pragma unroll
    for (int off = 32; off > 0; off >>= 1) s[rr] += __shfl_down(s[rr], off, 64);
    s[rr] = __shfl(s[rr], 0, 64);
  }

  int tg[4];
#pragma unroll
  for (int rr = 0; rr < 4; ++rr) tg[rr] = target[r0 + rr];

#pragma unroll
  for (int rr = 0; rr < 4; ++rr) {
    float inv = 1.0f / s[rr];
    float* row = out + (size_t)(r0 + rr) * C_DIM;
#pragma unroll
    for (int k = 0; k < 4; ++k) {
      int c = k * 256 + lane * 4;
      float lg[4];
#pragma unroll
      for (int i = 0; i < 4; ++i) {
        float p = v[rr][k * 4 + i] * inv;
        p = fminf(fmaxf(p, EPS32), 1.0f - EPS32);
        lg[i] = __logf(p);
        if (c + i == tg[rr]) rowloss[r0 + rr] = -lg[i];
      }
      if (c + 3 < C_DIM) {
        *(float4*)(row + c) = make_float4(lg[0], lg[1], lg[2], lg[3]);
      } else {
#pragma unroll
        for (int i = 0; i < 4; ++i) if (c + i < C_DIM) row[c + i] = lg[i];
      }
    }
  }
}

// ---- E: loss = mean(rowloss). One 1024-thread block, ILP-8, plain store.
__global__ __launch_bounds__(1024) void finalize(const float* __restrict__ rowloss,
                                                 float* __restrict__ out_loss) {
  int tid = threadIdx.x;
  float a[8];
#pragma unroll
  for (int j = 0; j < 8; ++j) a[j] = rowloss[tid + j * 1024];
  float s = 0.f;
#pragma unroll
  for (int j = 0; j < 8; ++j) s += a[j];
  s = wave_red(s);
  __shared__ float sm[16];
  if ((tid & 63) == 0) sm[tid >> 6] = s;
  __syncthreads();
  if (tid == 0) {
    float t = 0.f;
#pragma unroll
    for (int k = 0; k < 16; ++k) t += sm[k];
    out_loss[0] = t * (1.0f / B_ROWS);
  }
}

extern "C" void kernel_launch(void* const* d_in, const int* in_sizes, int n_in,
                              void* d_out, int out_size, void* d_ws, size_t ws_size,
                              hipStream_t stream) {
  const float* feature = (const float*)d_in[0];
  const float* cls_w   = (const float*)d_in[3];
  const float* cls_b   = (const float*)d_in[4];
  const float* eps     = (const float*)d_in[5];
  const int*   target  = (const int*)d_in[6];
  float* out = (float*)d_out;
  float* out_loss = out + (size_t)B_ROWS * C_DIM;

  char* ws = (char*)d_ws;
  __hip_bfloat16* z_bf    = (__hip_bfloat16*)ws;                // 33554432 B
  __hip_bfloat16* clsw_bf = (__hip_bfloat16*)(ws + 33554432);   //  4194304 B
  float*          rowloss = (float*)(ws + 33554432 + 4194304);  //    32768 B

  fuse_z<<<dim3(ZBLK + 1024), 256, 0, stream>>>((const float4*)feature, (const float4*)eps,
                                                (uint4*)z_bf, cls_w, clsw_bf);
  gemm_bt<<<dim3(B_ROWS / 128, C_PAD / 64), 256, 0, stream>>>(z_bf, clsw_bf, cls_b, out);
  rownorm<<<dim3(B_ROWS / 16), 256, 0, stream>>>(out, target, rowloss);
  finalize<<<dim3(1), 1024, 0, stream>>>(rowloss, out_loss);
}

// Round 10
// 240.527 us; speedup vs baseline: 1.0282x; 1.0282x over previous
//
#include <hip/hip_runtime.h>
#include <hip/hip_bf16.h>

#define B_ROWS 8192
#define D_DIM  2048
#define C_DIM  1000
#define C_PAD  1024

#define EPS32   1.1920928955078125e-07f
// GAMMA = 1/exp(100) ~ 3.7e-44. GAMMA*rex ~ 1e-40 << ulp(h3~6.9) ~ 4.8e-7,
// so loss == mean(h3) exactly in fp32. rex pipeline deleted (round 5).
// Round 12: rownorm 4 rows/wave, finalize 1024-thr — 232.5us (best).
// Round 13: gemm 128x64 single-buffer (4/CU) — gemm <54us. fuse_z frozen ~55.
// Round 14: explicit dbuf REGRESSED gemm 54->64.5 (m99/m100 null confirmed
// here too) — reverted to single-buffer.
// Round 15: rownorm DELETED via row-sum linearity: sum_c(z.w_c + b_c) =
// z.(sum_c w_c) + sum_c b_c. prep computes wsum/bsum; fuse_z computes
// rowsum[b] = dot(bf16(z_b), wsum) + bsum (idle-VALU kernel); gemm epilogue
// does normalize+clamp+log+rowloss in-place (idle-VALU DMA-bound kernel).
// out written once, never re-read.

typedef __attribute__((ext_vector_type(8))) short short8;   // 8 bf16 = 4 VGPRs
typedef __attribute__((ext_vector_type(4))) float f32x4;    // MFMA accumulator

#define GLOAD_LDS16(gptr, lptr) \
  __builtin_amdgcn_global_load_lds((const __attribute__((address_space(1))) void*)(gptr), \
                                   (__attribute__((address_space(3))) void*)(lptr), 16, 0, 0)

__device__ inline unsigned short f2bf(float x) {
  union { __hip_bfloat16 b; unsigned short u; } cv;
  cv.b = __float2bfloat16(x);
  return cv.u;
}

__device__ inline float bf2f(unsigned short u) {
  union { unsigned int i; float f; } c;
  c.i = (unsigned int)u << 16;
  return c.f;
}

__device__ inline float wave_red(float v) {
#pragma unroll
  for (int off = 32; off > 0; off >>= 1) v += __shfl_down(v, off, 64);
  return v;
}

// ---- prep: blocks [0,1024) cast cls_w -> bf16 padded [1024][2048];
//            blocks [1024,1088) wsum[col] = sum_{r<1000} cls_w[r][col] (32 cols/blk,
//            8-way row-split, LDS reduce, no atomics);
//            block 1088: bsum = sum(cls_b).
__global__ __launch_bounds__(256) void prep(const float* __restrict__ cls_w,
                                            __hip_bfloat16* __restrict__ clsw_bf,
                                            const float* __restrict__ cls_b,
                                            float* __restrict__ wsum,
                                            float* __restrict__ bsum) {
  int bid = blockIdx.x, tid = threadIdx.x;
  if (bid < 1024) {
    int j = (bid * 256 + tid) * 8;   // elem idx in [1024][2048]
    int row = j >> 11;
    int col = j & 2047;
    union { unsigned short u[8]; uint4 v; } pk;
    if (row < C_DIM) {
      const float* src = cls_w + (size_t)row * D_DIM + col;
#pragma unroll
      for (int i2 = 0; i2 < 8; ++i2) pk.u[i2] = f2bf(src[i2]);
    } else {
#pragma unroll
      for (int i2 = 0; i2 < 8; ++i2) pk.u[i2] = 0;
    }
    *(uint4*)((unsigned short*)clsw_bf + j) = pk.v;
  } else if (bid < 1088) {
    int k = bid - 1024;
    int col = k * 32 + (tid & 31);
    int g = tid >> 5;                 // 8 row-groups x 125 rows
    float s = 0.f;
    const float* p = cls_w + (size_t)(g * 125) * D_DIM + col;
#pragma unroll 5
    for (int rr = 0; rr < 125; ++rr) s += p[(size_t)rr * D_DIM];
    __shared__ float lsm[8][32];
    lsm[g][tid & 31] = s;
    __syncthreads();
    if (tid < 32) {
      float a = 0.f;
#pragma unroll
      for (int gg = 0; gg < 8; ++gg) a += lsm[gg][tid];
      wsum[k * 32 + tid] = a;
    }
  } else {
    float s = 0.f;
    int i0 = tid * 4;
    if (i0 < C_DIM)                   // 250 threads x 4 = 1000
      s = cls_b[i0] + cls_b[i0 + 1] + cls_b[i0 + 2] + cls_b[i0 + 3];
    s = wave_red(s);
    __shared__ float sm[4];
    if ((tid & 63) == 0) sm[tid >> 6] = s;
    __syncthreads();
    if (tid == 0) bsum[0] = sm[0] + sm[1] + sm[2] + sm[3];
  }
}

// ---- fuse_z: block b == z-row b. Pack z_bf = bf16(feature+eps) (16B store) and
// compute rowsum[b] = dot(bf16-rounded z, wsum) + bsum (block reduction).
__global__ __launch_bounds__(256) void fuse_z(const float4* __restrict__ f4,
                                              const float4* __restrict__ e4,
                                              uint4* __restrict__ z4,
                                              const float* __restrict__ wsum,
                                              const float* __restrict__ bsum,
                                              float* __restrict__ rowsum) {
  int bid = blockIdx.x, tid = threadIdx.x;
  int t = bid * 256 + tid;
  int i0 = t * 2;
  float4 f0 = f4[i0], f1 = f4[i0 + 1];
  float4 e0 = e4[i0], e1 = e4[i0 + 1];
  float4 w0 = *(const float4*)(wsum + tid * 8);
  float4 w1 = *(const float4*)(wsum + tid * 8 + 4);
  union { unsigned short u[8]; uint4 v; } pz;
  pz.u[0] = f2bf(f0.x + e0.x);
  pz.u[1] = f2bf(f0.y + e0.y);
  pz.u[2] = f2bf(f0.z + e0.z);
  pz.u[3] = f2bf(f0.w + e0.w);
  pz.u[4] = f2bf(f1.x + e1.x);
  pz.u[5] = f2bf(f1.y + e1.y);
  pz.u[6] = f2bf(f1.z + e1.z);
  pz.u[7] = f2bf(f1.w + e1.w);
  z4[t] = pz.v;

  float d = bf2f(pz.u[0]) * w0.x + bf2f(pz.u[1]) * w0.y +
            bf2f(pz.u[2]) * w0.z + bf2f(pz.u[3]) * w0.w +
            bf2f(pz.u[4]) * w1.x + bf2f(pz.u[5]) * w1.y +
            bf2f(pz.u[6]) * w1.z + bf2f(pz.u[7]) * w1.w;
  d = wave_red(d);
  __shared__ float sm[4];
  if ((tid & 63) == 0) sm[tid >> 6] = d;
  __syncthreads();
  if (tid == 0) rowsum[bid] = sm[0] + sm[1] + sm[2] + sm[3] + bsum[0];
}

// ---- gemm + fused epilogue: logits = log(clamp((z@W^T + b) / rowsum)).
// Round-13 proven single-buffer 128x64 tile (4 blocks/CU), BK=64, 4 waves 2x2,
// XOR-swizzle: 16B chunk (row, cc) at slot row*8 + (cc ^ (row&7)).
// Epilogue normalize+clamp+log runs on the 80%-idle VALU; out written ONCE.
__global__ __launch_bounds__(256) void gemm_bt(const __hip_bfloat16* __restrict__ A,
                                               const __hip_bfloat16* __restrict__ Bt,
                                               const float* __restrict__ cls_b,
                                               const float* __restrict__ rowsum,
                                               const int* __restrict__ target,
                                               float* __restrict__ out,
                                               float* __restrict__ rowloss) {
  __shared__ __align__(16) __hip_bfloat16 sA[128 * 64];   // 16 KB
  __shared__ __align__(16) __hip_bfloat16 sB[64 * 64];    //  8 KB
  const int tid = threadIdx.x;
  const int m0 = blockIdx.x * 128;
  const int n0 = blockIdx.y * 64;
  const int w = tid >> 6, lane = tid & 63;
  const int wm = (w & 1) * 64, wn = (w >> 1) * 32;
  const int l15 = lane & 15, quad = lane >> 4;

  f32x4 acc[4][2] = {};

  for (int k0 = 0; k0 < D_DIM; k0 += 64) {
#pragma unroll
    for (int i = 0; i < 4; ++i) {
      int j = i * 256 + tid;          // A: 1024 chunks of 16B (128 rows x 8)
      int row = j >> 3;
      int cc = (j & 7) ^ (row & 7);   // inverse of the swizzle (XOR involution)
      GLOAD_LDS16(A + (size_t)(m0 + row) * D_DIM + k0 + cc * 8, &sA[j * 8]);
    }
#pragma unroll
    for (int i = 0; i < 2; ++i) {
      int j = i * 256 + tid;          // B: 512 chunks (64 rows x 8)
      int row = j >> 3;
      int cc = (j & 7) ^ (row & 7);
      GLOAD_LDS16(Bt + (size_t)(n0 + row) * D_DIM + k0 + cc * 8, &sB[j * 8]);
    }
    __syncthreads();
#pragma unroll
    for (int kk = 0; kk < 64; kk += 32) {
      const int ccr = (kk >> 3) + quad;   // which 8-elem chunk along K
      short8 af[4], bfr[2];
#pragma unroll
      for (int i = 0; i < 4; ++i) {
        int r = wm + i * 16 + l15;
        af[i] = *(const short8*)&sA[(r * 8 + (ccr ^ (r & 7))) * 8];
      }
#pragma unroll
      for (int jn = 0; jn < 2; ++jn) {
        int r = wn + jn * 16 + l15;
        bfr[jn] = *(const short8*)&sB[(r * 8 + (ccr ^ (r & 7))) * 8];
      }
#pragma unroll
      for (int i = 0; i < 4; ++i)
#pragma unroll
        for (int jn = 0; jn < 2; ++jn)
          acc[i][jn] = __builtin_amdgcn_mfma_f32_16x16x32_bf16(af[i], bfr[jn], acc[i][jn], 0, 0, 0);
    }
    __syncthreads();
  }

  // fused epilogue: C/D layout col=lane&15, row=quad*4+reg (m89-verified)
  float bias[2]; int bcol[2];
#pragma unroll
  for (int jn = 0; jn < 2; ++jn) {
    bcol[jn] = n0 + wn + jn * 16 + l15;
    bias[jn] = (bcol[jn] < C_DIM) ? cls_b[bcol[jn]] : 0.f;
  }
#pragma unroll
  for (int i = 0; i < 4; ++i) {
#pragma unroll
    for (int r = 0; r < 4; ++r) {
      int row = m0 + wm + i * 16 + quad * 4 + r;
      float inv = 1.0f / rowsum[row];
      int tg = target[row];
      float* orow = out + (size_t)row * C_DIM;
#pragma unroll
      for (int jn = 0; jn < 2; ++jn) {
        int col = bcol[jn];
        if (col < C_DIM) {
          float p = (acc[i][jn][r] + bias[jn]) * inv;
          p = fminf(fmaxf(p, EPS32), 1.0f - EPS32);
          float lg = __logf(p);
          orow[col] = lg;
          if (col == tg) rowloss[row] = -lg;
        }
      }
    }
  }
}

// ---- finalize: loss = mean(rowloss). One 1024-thread block, ILP-8, plain store.
__global__ __launch_bounds__(1024) void finalize(const float* __restrict__ rowloss,
                                                 float* __restrict__ out_loss) {
  int tid = threadIdx.x;
  float a[8];
#pragma unroll
  for (int j = 0; j < 8; ++j) a[j] = rowloss[tid + j * 1024];
  float s = 0.f;
#pragma unroll
  for (int j = 0; j < 8; ++j) s += a[j];
  s = wave_red(s);
  __shared__ float sm[16];
  if ((tid & 63) == 0) sm[tid >> 6] = s;
  __syncthreads();
  if (tid == 0) {
    float t = 0.f;
#pragma unroll
    for (int k = 0; k < 16; ++k) t += sm[k];
    out_loss[0] = t * (1.0f / B_ROWS);
  }
}

extern "C" void kernel_launch(void* const* d_in, const int* in_sizes, int n_in,
                              void* d_out, int out_size, void* d_ws, size_t ws_size,
                              hipStream_t stream) {
  const float* feature = (const float*)d_in[0];
  const float* cls_w   = (const float*)d_in[3];
  const float* cls_b   = (const float*)d_in[4];
  const float* eps     = (const float*)d_in[5];
  const int*   target  = (const int*)d_in[6];
  float* out = (float*)d_out;
  float* out_loss = out + (size_t)B_ROWS * C_DIM;

  char* ws = (char*)d_ws;
  __hip_bfloat16* z_bf    = (__hip_bfloat16*)ws;                   // 33554432 B
  __hip_bfloat16* clsw_bf = (__hip_bfloat16*)(ws + 33554432);      //  4194304 B
  float*          rowloss = (float*)(ws + 37748736);               //    32768 B
  float*          rowsum  = (float*)(ws + 37781504);               //    32768 B
  float*          wsum    = (float*)(ws + 37814272);               //     8192 B
  float*          bsum    = (float*)(ws + 37822464);               //      256 B

  prep<<<dim3(1024 + 64 + 1), 256, 0, stream>>>(cls_w, clsw_bf, cls_b, wsum, bsum);
  fuse_z<<<dim3(B_ROWS), 256, 0, stream>>>((const float4*)feature, (const float4*)eps,
                                           (uint4*)z_bf, wsum, bsum, rowsum);
  gemm_bt<<<dim3(B_ROWS / 128, C_PAD / 64), 256, 0, stream>>>(z_bf, clsw_bf, cls_b,
                                                              rowsum, target, out, rowloss);
  finalize<<<dim3(1), 1024, 0, stream>>>(rowloss, out_loss);
}